// Round 6
// baseline (354.167 us; speedup 1.0000x reference)
//
#include <hip/hip_runtime.h>
#include <hip/hip_bf16.h>
#include <math.h>

#define ZD_ 64
#define HID_ 256
#define NW2_ 49152                    // OC*IC*KW columns of W2
#define W2D_OUT 37748736              // O*I*KW*L (out dwords, main region)

typedef short bf16x8 __attribute__((ext_vector_type(8)));
typedef float f32x4 __attribute__((ext_vector_type(4)));

static __device__ __forceinline__ unsigned short f2bf(float f) {
    union { float f; unsigned u; } v; v.f = f;
    unsigned r = v.u + 0x7FFF + ((v.u >> 16) & 1);   // RNE
    return (unsigned short)(r >> 16);
}

static __device__ __forceinline__ unsigned pack2(float lo, float hi) {
    return (unsigned)f2bf(lo) | ((unsigned)f2bf(hi) << 16);
}

// ---------------------------------------------------------------------------
// Prep: unchanged (measured ~4 us).
// ---------------------------------------------------------------------------
__global__ void prep_kernel(const float* __restrict__ Z,
                            const float* __restrict__ pde,
                            const float* __restrict__ W1,
                            const float* __restrict__ U1,
                            const float* __restrict__ b1,
                            const float* __restrict__ z_bias,
                            const float* __restrict__ u_bias,
                            unsigned short* __restrict__ hiddenA,
                            float* __restrict__ out_bb) {
    __shared__ float part[16][64];
    __shared__ float meanv[64];
    __shared__ float zr[64];
    const int t = threadIdx.x, m = blockIdx.x;
    if (t < 64) zr[t] = Z[m * ZD_ + t];
    const int c4 = t & 15, rg = t >> 4;
    float sx = 0.f, sy = 0.f, sz = 0.f, sw = 0.f;
    const float4* p = (const float4*)pde;      // 16 float4 per 64-col row
    for (int r = 0; r < 64; ++r) {
        float4 v = p[(rg * 64 + r) * 16 + c4];
        sx += v.x; sy += v.y; sz += v.z; sw += v.w;
    }
    part[rg][c4 * 4 + 0] = sx; part[rg][c4 * 4 + 1] = sy;
    part[rg][c4 * 4 + 2] = sz; part[rg][c4 * 4 + 3] = sw;
    __syncthreads();
    if (t < 64) {
        float a = 0.f;
        #pragma unroll
        for (int g = 0; g < 16; ++g) a += part[g][t];
        meanv[t] = a * (1.f / 1024.f);
    }
    __syncthreads();
    float f = b1[t];
    #pragma unroll
    for (int d = 0; d < 64; ++d) f = fmaf(meanv[d], U1[d * HID_ + t], f);
    float s = f;
    #pragma unroll
    for (int d = 0; d < 64; ++d) s = fmaf(zr[d], W1[d * HID_ + t], s);
    // MFMA-A-native layout: hiddenA[(k/8)*256 + m][k%8]
    hiddenA[((size_t)(t >> 3) * 256 + m) * 8 + (t & 7)] = f2bf(tanhf(s));
    if (m < 8) {
        const int idx = m * 256 + t;
        out_bb[idx] = z_bias[idx] + u_bias[idx];
    }
}

// ---------------------------------------------------------------------------
// Fused MFMA GEMM + expansion, v3: TRUE occupancy test — 32 waves/CU.
// grid 1024: b -> mh = b&1, icq = (b>>1)&3, oc = b>>3.
// 512 threads = 8 waves; wave w owns m-tile mt = mh*8 + w (one 16-row tile).
// K staged in 2 chunks of 128 (LDS 25.5 KB -> 4 blocks/CU).
// Traffic pattern, swizzles, accumulation order identical to R2 per output.
// Epilogue: LDS-bounce in 2 passes of 8 kc-rows (fits reused staging LDS).
// ---------------------------------------------------------------------------
#define BT_SC 68                      // staging row stride in DWORDS (chunked)
#define WL_ST 97                      // bounce row stride in dwords
#define WL_SZ 776                     // 8*97 per wave

__global__ __launch_bounds__(512, 8)
void gemm_expand(const unsigned short* __restrict__ hiddenA,
                 const float* __restrict__ W2,
                 const float* __restrict__ b2,
                 const float* __restrict__ unet,
                 float* __restrict__ out) {
    __shared__ unsigned bT[96 * BT_SC];        // 26112 B (>= 8*WL_SZ*4 = 24832)

    const int t = threadIdx.x;
    const int lane = t & 63;
    const int wave = t >> 6;                  // 0..7
    const int n15 = lane & 15;
    const int quad = lane >> 4;
    const int L = lane & 31;
    const int half = lane >> 5;
    const int mh  = blockIdx.x & 1;
    const int icq = (blockIdx.x >> 1) & 3;
    const int oc  = blockIdx.x >> 3;
    const int n0g = oc * 384 + icq * 96;
    const int mt  = mh * 8 + wave;            // m-tile 0..15

    f32x4 acc[6];
    #pragma unroll
    for (int b = 0; b < 6; ++b) acc[b] = (f32x4){0.f, 0.f, 0.f, 0.f};

    for (int c = 0; c < 2; ++c) {
        // ---- stage chunk: 96n x 128k of W2, k-pair packed bf16 ----
        #pragma unroll
        for (int i = 0; i < 3; ++i) {
            const int u   = i * 512 + t;      // 0..1535 units
            const int kpl = u / 24;           // 0..63 (chunk-local k-pair)
            const int nq  = u - kpl * 24;     // 0..23
            const int kg  = c * 128 + 2 * kpl;
            const float* p0 = W2 + (size_t)kg * NW2_ + n0g + nq * 4;
            const float4 va = *(const float4*)p0;
            const float4 vb = *(const float4*)(p0 + NW2_);
            const int kpx = kpl ^ ((nq & 7) << 1) ^ (((nq >> 3) & 1) << 4);
            unsigned* r0 = &bT[(4 * nq) * BT_SC + kpx];
            r0[0 * BT_SC] = pack2(va.x, vb.x);
            r0[1 * BT_SC] = pack2(va.y, vb.y);
            r0[2 * BT_SC] = pack2(va.z, vb.z);
            r0[3 * BT_SC] = pack2(va.w, vb.w);
        }
        __syncthreads();

        // ---- MFMA: 4 k-steps of 32 ----
        #pragma unroll
        for (int ksl = 0; ksl < 4; ++ksl) {
            const int g = (c * 4 + ksl) * 4 + quad;   // 8-k group 0..31
            const bf16x8 afr = *(const bf16x8*)(hiddenA +
                      ((size_t)g * 256 + mt * 16 + n15) * 8);
            const int base4 = ksl * 16 + quad * 4;    // chunk-local kp base
            #pragma unroll
            for (int nt = 0; nt < 6; ++nt) {
                const int n = nt * 16 + n15;
                const int nqr = n >> 2;
                const int swz = ((nqr & 7) << 1) ^ (((nqr >> 3) & 1) << 4);
                const unsigned* row = &bT[n * BT_SC];
                union { bf16x8 v; unsigned long long q[2]; } bb;
                bb.q[0] = *(const unsigned long long*)&row[(base4)     ^ swz];
                bb.q[1] = *(const unsigned long long*)&row[(base4 + 2) ^ swz];
                acc[nt] = __builtin_amdgcn_mfma_f32_16x16x32_bf16(afr, bb.v, acc[nt], 0, 0, 0);
            }
        }
        __syncthreads();                      // safe to restage / reuse bT
    }

    // ---- b2 for this wave's 96 columns ----
    float gb2v[6];
    #pragma unroll
    for (int nt = 0; nt < 6; ++nt) gb2v[nt] = b2[n0g + nt * 16 + n15];

    // ---- epilogue: 2 passes of 8 kc-rows through wave-private LDS ----
    float* wl = ((float*)bT) + wave * WL_SZ;  // 8 x 97 f32, wave-private

    const int o = mt * 128 + oc;
    const float* uo = unet + (size_t)o * 6144;
    float* ob = out + (size_t)o * 18432;

    #pragma unroll
    for (int p = 0; p < 2; ++p) {
        // produce: rows kc = p*8 + (quad&1)*4 + r, written by quads with quad>>1 == p
        if ((quad >> 1) == p) {
            #pragma unroll
            for (int nt = 0; nt < 6; ++nt)
                #pragma unroll
                for (int r = 0; r < 4; ++r)
                    wl[((quad & 1) * 4 + r) * WL_ST + nt * 16 + n15] = acc[nt][r] + gb2v[nt];
        }
        // wave-private LDS; per-wave DS ops in-order, compiler inserts waits

        // drain: 4 kp-rounds; per instr each 32-lane half writes 128B contiguous
        #pragma unroll
        for (int kp = 0; kp < 4; ++kp) {
            const int r8 = kp * 2 + half;     // wl row 0..7
            const int kc = p * 8 + r8;        // global kc 0..15
            const float* wrow = wl + r8 * WL_ST;
            const float* ub = uo + kc * 384 + icq * 96;
            float* os = ob + kc * 1152 + icq * 288;
            #pragma unroll
            for (int j = 0; j < 9; ++j) {
                const int d  = j * 32 + L;    // 0..287 within the run
                const int d3 = d / 3;         // = ic_rel*3 + kw  (w column)
                const int d9 = d / 9;         // = ic_rel
                const int l  = d - 3 * d3;    // = l
                os[d] = wrow[d3] * ub[d9 * 3 + l];
            }
        }
    }
}

// ---------------------------------------------------------------------------
extern "C" void kernel_launch(void* const* d_in, const int* in_sizes, int n_in,
                              void* d_out, int out_size, void* d_ws, size_t ws_size,
                              hipStream_t stream) {
    const float* Z       = (const float*)d_in[0];
    const float* z_bias  = (const float*)d_in[1];
    const float* unet_w  = (const float*)d_in[2];
    const float* unet_b  = (const float*)d_in[3];
    const float* pde     = (const float*)d_in[4];
    const float* W1      = (const float*)d_in[5];
    const float* U1      = (const float*)d_in[6];
    const float* b1      = (const float*)d_in[7];
    const float* W2      = (const float*)d_in[8];
    const float* b2      = (const float*)d_in[9];
    float* out = (float*)d_out;

    unsigned short* hiddenA = (unsigned short*)d_ws;   // 256*256 bf16 = 128 KB

    prep_kernel<<<256, 256, 0, stream>>>(Z, pde, W1, U1, b1, z_bias, unet_b,
                                         hiddenA, out + W2D_OUT);
    gemm_expand<<<1024, 512, 0, stream>>>(hiddenA, W2, b2, unet_w, out);
}

// Round 7
// 312.224 us; speedup vs baseline: 1.1343x; 1.1343x over previous
//
#include <hip/hip_runtime.h>
#include <hip/hip_bf16.h>
#include <math.h>

#define ZD_ 64
#define HID_ 256
#define NW2_ 49152                    // OC*IC*KW columns of W2
#define W2D_OUT 37748736              // O*I*KW*L (out dwords, main region)

typedef short bf16x8 __attribute__((ext_vector_type(8)));
typedef float f32x4 __attribute__((ext_vector_type(4)));

static __device__ __forceinline__ unsigned short f2bf(float f) {
    union { float f; unsigned u; } v; v.f = f;
    unsigned r = v.u + 0x7FFF + ((v.u >> 16) & 1);   // RNE
    return (unsigned short)(r >> 16);
}

static __device__ __forceinline__ unsigned pack2(float lo, float hi) {
    return (unsigned)f2bf(lo) | ((unsigned)f2bf(hi) << 16);
}

// ---------------------------------------------------------------------------
// Prep: unchanged (measured ~4 us).
// ---------------------------------------------------------------------------
__global__ void prep_kernel(const float* __restrict__ Z,
                            const float* __restrict__ pde,
                            const float* __restrict__ W1,
                            const float* __restrict__ U1,
                            const float* __restrict__ b1,
                            const float* __restrict__ z_bias,
                            const float* __restrict__ u_bias,
                            unsigned short* __restrict__ hiddenA,
                            float* __restrict__ out_bb) {
    __shared__ float part[16][64];
    __shared__ float meanv[64];
    __shared__ float zr[64];
    const int t = threadIdx.x, m = blockIdx.x;
    if (t < 64) zr[t] = Z[m * ZD_ + t];
    const int c4 = t & 15, rg = t >> 4;
    float sx = 0.f, sy = 0.f, sz = 0.f, sw = 0.f;
    const float4* p = (const float4*)pde;      // 16 float4 per 64-col row
    for (int r = 0; r < 64; ++r) {
        float4 v = p[(rg * 64 + r) * 16 + c4];
        sx += v.x; sy += v.y; sz += v.z; sw += v.w;
    }
    part[rg][c4 * 4 + 0] = sx; part[rg][c4 * 4 + 1] = sy;
    part[rg][c4 * 4 + 2] = sz; part[rg][c4 * 4 + 3] = sw;
    __syncthreads();
    if (t < 64) {
        float a = 0.f;
        #pragma unroll
        for (int g = 0; g < 16; ++g) a += part[g][t];
        meanv[t] = a * (1.f / 1024.f);
    }
    __syncthreads();
    float f = b1[t];
    #pragma unroll
    for (int d = 0; d < 64; ++d) f = fmaf(meanv[d], U1[d * HID_ + t], f);
    float s = f;
    #pragma unroll
    for (int d = 0; d < 64; ++d) s = fmaf(zr[d], W1[d * HID_ + t], s);
    // MFMA-A-native layout: hiddenA[(k/8)*256 + m][k%8]
    hiddenA[((size_t)(t >> 3) * 256 + m) * 8 + (t & 7)] = f2bf(tanhf(s));
    if (m < 8) {
        const int idx = m * 256 + t;
        out_bb[idx] = z_bias[idx] + u_bias[idx];
    }
}

// ---------------------------------------------------------------------------
// Fused MFMA GEMM + expansion, v4: single-owner traffic + contiguous writes.
// grid 256: b -> oc = b>>1 (0..127), mh = b&1 (m-half).  1024 thr = 16 waves.
// Block owns ALL 384 n-cols of its oc and 128 m-rows (8 h-tiles).
//   -> W2 read once grid-wide; unet read once; out[o] rows single-owner,
//      written as complementary 2304B-contiguous runs tiling 73728B in order.
// Wave (mi = w>>1, nh = w&1): h-tile mt = mh*8+mi, n-half nh (12 n-tiles).
// K staged in 4 chunks of 64 (proven swizzle); epilogue = 2-pass wave-private
// LDS bounce (aliases bT after the final barrier).
// ---------------------------------------------------------------------------
#define BT_ST 34                      // staging row stride in DWORDS
#define WL_ST 193                     // bounce row stride in dwords
#define WL_SZ 1544                    // 8*193 per wave

__global__ __launch_bounds__(1024, 4)
void gemm_expand(const unsigned short* __restrict__ hiddenA,
                 const float* __restrict__ W2,
                 const float* __restrict__ b2,
                 const float* __restrict__ unet,
                 float* __restrict__ out) {
    __shared__ unsigned buf[24704];            // 98816 B (bT: 13056 dw; wl: 24704 dw)

    const int t = threadIdx.x;
    const int lane = t & 63;
    const int wave = t >> 6;                  // 0..15
    const int n15 = lane & 15;
    const int quad = lane >> 4;
    const int mi = wave >> 1;                 // 0..7
    const int nh = wave & 1;                  // 0..1
    const int oc = blockIdx.x >> 1;
    const int mh = blockIdx.x & 1;
    const int n0g = oc * 384;
    const int mt = mh * 8 + mi;               // h-tile 0..15

    unsigned* bT = buf;

    f32x4 acc[12];
    #pragma unroll
    for (int b = 0; b < 12; ++b) acc[b] = (f32x4){0.f, 0.f, 0.f, 0.f};

    for (int c = 0; c < 4; ++c) {
        // ---- stage chunk: 384n x 64k of W2, k-pair packed bf16 ----
        #pragma unroll
        for (int i = 0; i < 3; ++i) {
            const int u  = i * 1024 + t;      // 0..3071 units
            const int kp = u / 96;            // 0..31 (chunk-local k-pair)
            const int nq = u - kp * 96;       // 0..95 -> n = 4nq..4nq+3
            const float* p0 = W2 + (size_t)(c * 64 + 2 * kp) * NW2_ + n0g + nq * 4;
            const float4 va = *(const float4*)p0;          // k even
            const float4 vb = *(const float4*)(p0 + NW2_); // k odd
            const int kpx = kp ^ ((nq & 7) << 1) ^ (((nq >> 3) & 1) << 4);
            unsigned* r0 = &bT[(4 * nq) * BT_ST + kpx];
            r0[0 * BT_ST] = pack2(va.x, vb.x);
            r0[1 * BT_ST] = pack2(va.y, vb.y);
            r0[2 * BT_ST] = pack2(va.z, vb.z);
            r0[3 * BT_ST] = pack2(va.w, vb.w);
        }
        __syncthreads();

        // ---- MFMA: 2 k-steps of 32 ----
        #pragma unroll
        for (int ksl = 0; ksl < 2; ++ksl) {
            const int g = c * 8 + ksl * 4 + quad;     // 8-k group 0..31
            const bf16x8 afr = *(const bf16x8*)(hiddenA +
                      ((size_t)g * 256 + mt * 16 + n15) * 8);
            const int base4 = ksl * 16 + quad * 4;    // chunk-local kp base
            #pragma unroll
            for (int nt = 0; nt < 12; ++nt) {
                const int n = nh * 192 + nt * 16 + n15;
                const int nqr = n >> 2;
                const int swz = ((nqr & 7) << 1) ^ (((nqr >> 3) & 1) << 4);
                const unsigned* row = &bT[n * BT_ST];
                union { bf16x8 v; unsigned long long q[2]; } bb;
                bb.q[0] = *(const unsigned long long*)&row[(base4)     ^ swz];
                bb.q[1] = *(const unsigned long long*)&row[(base4 + 2) ^ swz];
                acc[nt] = __builtin_amdgcn_mfma_f32_16x16x32_bf16(afr, bb.v, acc[nt], 0, 0, 0);
            }
        }
        __syncthreads();                      // also protects bT/wl aliasing
    }

    // ---- b2 for this wave's 192 columns ----
    float gb2v[12];
    #pragma unroll
    for (int nt = 0; nt < 12; ++nt) gb2v[nt] = b2[n0g + nh * 192 + nt * 16 + n15];

    // ---- epilogue: 2 passes of 8 kc-rows through wave-private LDS ----
    float* wl = ((float*)buf) + wave * WL_SZ; // 8 x 193 f32, wave-private

    const int o = mt * 128 + oc;
    const float* uo = unet + (size_t)o * 6144 + nh * 192;
    float* ob = out + (size_t)o * 18432 + nh * 576;

    #pragma unroll
    for (int p = 0; p < 2; ++p) {
        // produce: rows kc = p*8 + (quad&1)*4 + r, by quads with quad>>1 == p
        if ((quad >> 1) == p) {
            #pragma unroll
            for (int nt = 0; nt < 12; ++nt)
                #pragma unroll
                for (int r = 0; r < 4; ++r)
                    wl[((quad & 1) * 4 + r) * WL_ST + nt * 16 + n15] = acc[nt][r] + gb2v[nt];
        }
        // wave-private LDS; per-wave DS ops in-order, compiler inserts waits

        // drain: per kc one 576-dword (2304B) contiguous run; 64 lanes x 4B
        // per instr = 256B contiguous; the two nh waves tile out[o] fully.
        #pragma unroll
        for (int r8 = 0; r8 < 8; ++r8) {
            const int kc = p * 8 + r8;        // 0..15
            const float* wrow = wl + r8 * WL_ST;
            const float* ub = uo + kc * 384;
            float* os = ob + kc * 1152;
            #pragma unroll
            for (int j = 0; j < 9; ++j) {
                const int d  = j * 64 + lane; // 0..575 within the run
                const int d3 = d / 3;         // w column (local 0..191)
                const int d9 = d / 9;         // ic_rel 0..63
                const int l  = d - 3 * d3;    // l
                os[d] = wrow[d3] * ub[d9 * 3 + l];
            }
        }
    }
}

// ---------------------------------------------------------------------------
extern "C" void kernel_launch(void* const* d_in, const int* in_sizes, int n_in,
                              void* d_out, int out_size, void* d_ws, size_t ws_size,
                              hipStream_t stream) {
    const float* Z       = (const float*)d_in[0];
    const float* z_bias  = (const float*)d_in[1];
    const float* unet_w  = (const float*)d_in[2];
    const float* unet_b  = (const float*)d_in[3];
    const float* pde     = (const float*)d_in[4];
    const float* W1      = (const float*)d_in[5];
    const float* U1      = (const float*)d_in[6];
    const float* b1      = (const float*)d_in[7];
    const float* W2      = (const float*)d_in[8];
    const float* b2      = (const float*)d_in[9];
    float* out = (float*)d_out;

    unsigned short* hiddenA = (unsigned short*)d_ws;   // 256*256 bf16 = 128 KB

    prep_kernel<<<256, 256, 0, stream>>>(Z, pde, W1, U1, b1, z_bias, unet_b,
                                         hiddenA, out + W2D_OUT);
    gemm_expand<<<256, 1024, 0, stream>>>(hiddenA, W2, b2, unet_w, out);
}